// Round 13
// baseline (1246.478 us; speedup 1.0000x reference)
//
#include <hip/hip_runtime.h>

// Batched complex QR (Householder, LAPACK clarfg/cgeqr2 convention).
// v13: v12 code, waves_per_eu(3) -> (4) min-only.
// Round-12 post-mortem: spill-free at (3) (FETCH/WRITE compulsory 135/262MB)
// but occupancy 26.5% / VALUBusy 62% — ~8k of 20.8k cycles/wave are stalls
// on the per-step DS chain, covered by only ~3 resident waves/SIMD.
// Occupancy is the binding constraint ((2,2)=18.7%/51%/326us vs
// (3)=27%/62%/277us). The fused-P-update live set (~120 values) fits a
// 128-reg budget -> request 4 waves/EU. Guard metric: WRITE_SIZE must stay
// ~262MB (no spill); if it grows, revert.
//
// Layout recap: lane = g*16 + c; lane holds rows [16g,16g+16) of column c
// as 8 float2 row-pairs; v_pk_fma_f32 throughout; incremental norm downdate;
// unnormalized u + ds_swizzle (I<<5)|0x10 broadcasts; solve-push with
// Rbc=beta-1 trick; fp64 inline redo for |Re(alpha_i)| < 2e-4 (~0.26%).

constexpr int Mrows = 64;
constexpr int Rcols = 16;

typedef int v2i __attribute__((ext_vector_type(2)));
typedef float v2f __attribute__((ext_vector_type(2)));

#if defined(__has_builtin)
#if __has_builtin(__builtin_amdgcn_permlane16_swap)
#define USE_PL16 1
#else
#define USE_PL16 0
#endif
#if __has_builtin(__builtin_amdgcn_permlane32_swap)
#define USE_PL32 1
#else
#define USE_PL32 0
#endif
#else
#define USE_PL16 0
#define USE_PL32 0
#endif

__device__ __forceinline__ float rdlane(float v, int srclane) {
  return __int_as_float(__builtin_amdgcn_readlane(__float_as_int(v), srclane));
}

// v[l] + v[l^16]  (column-preserving: (g,c) <-> (g^1,c))
__device__ __forceinline__ float plswap16_addf(float v) {
#if USE_PL16
  v2i r = __builtin_amdgcn_permlane16_swap(__float_as_int(v), __float_as_int(v),
                                           false, false);
  return __int_as_float(r[0]) + __int_as_float(r[1]);
#else
  return v + __shfl_xor(v, 16, 64);
#endif
}

// v[l] + v[l^32]  ((g,c) <-> (g^2,c))
__device__ __forceinline__ float plswap32_addf(float v) {
#if USE_PL32
  v2i r = __builtin_amdgcn_permlane32_swap(__float_as_int(v), __float_as_int(v),
                                           false, false);
  return __int_as_float(r[0]) + __int_as_float(r[1]);
#else
  return v + __shfl_xor(v, 32, 64);
#endif
}

// Packed fp32 fma: one v_pk_fma_f32 per call.
__device__ __forceinline__ v2f pkfma(v2f a, v2f b, v2f c) {
#if defined(__has_builtin) && __has_builtin(__builtin_elementwise_fma)
  return __builtin_elementwise_fma(a, b, c);
#else
  v2f r;
  r[0] = fmaf(a[0], b[0], c[0]);
  r[1] = fmaf(a[1], b[1], c[1]);
  return r;
#endif
}

__device__ __forceinline__ v2f splat2(float s) { v2f r; r[0] = s; r[1] = s; return r; }

// ds_swizzle with compile-time immediate (builtin requires a literal const).
template <int IMM>
__device__ __forceinline__ float dswz(float v) {
  return __int_as_float(__builtin_amdgcn_ds_swizzle(__float_as_int(v), IMM));
}

// ---------------- fp64 helpers (proven v8/v9 path, unchanged) ----------------
template <int CTRL, int RM>
__device__ __forceinline__ double dpp_dadd(double v) {
  union { double d; int i[2]; } u, s;
  u.d = v;
  s.i[0] = __builtin_amdgcn_update_dpp(0, u.i[0], CTRL, RM, 0xF, true);
  s.i[1] = __builtin_amdgcn_update_dpp(0, u.i[1], CTRL, RM, 0xF, true);
  return v + s.d;
}

__device__ __forceinline__ double rdlaned(double v, int srclane) {
  union { double d; int i[2]; } u, r;
  u.d = v;
  r.i[0] = __builtin_amdgcn_readlane(u.i[0], srclane);
  r.i[1] = __builtin_amdgcn_readlane(u.i[1], srclane);
  return r.d;
}

__device__ __forceinline__ double wsum64d_fast(double v) {
  v = dpp_dadd<0xB1, 0xF>(v);
  v = dpp_dadd<0x4E, 0xF>(v);
  v = dpp_dadd<0x141, 0xF>(v);
  v = dpp_dadd<0x140, 0xF>(v);
  v = dpp_dadd<0x142, 0xA>(v);
  v = dpp_dadd<0x143, 0xC>(v);
  return rdlaned(v, 63);
}

// =====================================================================
// FP64 redo (rare, ~0.26% of waves): old row-per-lane layout, proven.
// =====================================================================
__device__ void qr_f64_fused(const float* __restrict__ x,
                             float* __restrict__ out, int b, int lane) {
  const float4* xp = reinterpret_cast<const float4*>(
      x + (size_t)b * (Mrows * Rcols * 2) + (size_t)lane * (Rcols * 2));
  double xr[Rcols], xi[Rcols], ar[Rcols], ai[Rcols];
#pragma unroll
  for (int k = 0; k < Rcols / 2; ++k) {
    float4 t = xp[k];
    xr[2 * k] = (double)t.x;      xi[2 * k] = (double)t.y;
    xr[2 * k + 1] = (double)t.z;  xi[2 * k + 1] = (double)t.w;
  }
#pragma unroll
  for (int j = 0; j < Rcols; ++j) { ar[j] = xr[j]; ai[j] = xi[j]; }

#pragma unroll
  for (int i = 0; i < Rcols; ++i) {
    double cr = ar[i], ci = ai[i];
    double sq = (lane > i) ? (cr * cr + ci * ci) : 0.0;
    double xnorm2 = wsum64d_fast(sq);
    double alphr = rdlaned(cr, i);
    double alphi = rdlaned(ci, i);

    double tr, ti;
    if (xnorm2 == 0.0 && alphi == 0.0) {
      tr = 0.0;  ti = 0.0;
    } else {
      double nrm = sqrt(alphr * alphr + alphi * alphi + xnorm2);
      double beta = (alphr >= 0.0) ? -nrm : nrm;
      double rb = 1.0 / beta;
      tr = (beta - alphr) * rb;
      ti = -alphi * rb;
      double dr = alphr - beta, di = alphi;
      double inv = 1.0 / (dr * dr + di * di);
      double sr = dr * inv, si = -di * inv;
      if (lane > i) {
        double nr = cr * sr - ci * si;
        double ni = cr * si + ci * sr;
        ar[i] = nr;
        ai[i] = ni;
      }
      if (lane == i) { ar[i] = beta; ai[i] = 0.0; }
    }

    double vr = (lane == i) ? 1.0 : ((lane > i) ? ar[i] : 0.0);
    double vi = (lane == i) ? 0.0 : ((lane > i) ? ai[i] : 0.0);
    const double ctr = tr, cti = -ti;
#pragma unroll
    for (int j = i + 1; j < Rcols; ++j) {
      double pr = fma(vr, ar[j], vi * ai[j]);
      double pi = fma(vr, ai[j], -(vi * ar[j]));
      pr = wsum64d_fast(pr);
      pi = wsum64d_fast(pi);
      double wr = fma(ctr, pr, -(cti * pi));
      double wi = fma(ctr, pi, cti * pr);
      ar[j] = fma(-wr, vr, fma(wi, vi, ar[j]));
      ai[j] = fma(-wr, vi, fma(-wi, vr, ai[j]));
    }

    double swr = xr[i], swi = xi[i];
#pragma unroll
    for (int k = 0; k < Rcols; ++k) {
      if (k >= i) break;
      double rr = rdlaned(ar[i], k);
      double ri = rdlaned(ai[i], k);
      swr = fma(-xr[k], rr, fma(xi[k], ri, swr));
      swi = fma(-xr[k], ri, fma(-xi[k], rr, swi));
    }
    double rbd = 1.0 / rdlaned(ar[i], i);
    xr[i] = swr * rbd;
    xi[i] = swi * rbd;
  }

  float4* op = reinterpret_cast<float4*>(
      out + (size_t)b * (Mrows * Rcols * 2) + (size_t)lane * (Rcols * 2));
#pragma unroll
  for (int k = 0; k < Rcols / 2; ++k) {
    op[k] = make_float4((float)xr[2 * k], (float)xi[2 * k],
                        (float)xr[2 * k + 1], (float)xi[2 * k + 1]);
  }
}

// =====================================================================
// One Householder step, (g,c) layout, row-pair packed. I compile-time.
// S = per-lane running norm^2 of own column over rows >= I (downdated).
// =====================================================================
template <int I>
__device__ __forceinline__ void qr_step(int lane,
                                        v2f (&Ar2)[8], v2f (&Ai2)[8],
                                        v2f (&Pr2)[8], v2f (&Pi2)[8],
                                        float& S, int bpaR, bool& risky) {
  const int c = lane & 15;
  const bool g0 = (lane < 16);
  constexpr int IH = I / 2;
  constexpr int ILo = I % 2;
  constexpr int SWZ = (I << 5) | 0x10;  // src = (l & 0x10) | I, g-preserving
  const v2f z2 = splat2(0.f);

  // ---- alpha and trailing norm (from downdated S) ----
  float alphr = rdlane(Ar2[IH][ILo], I);  // A[I][I]: lane I=(g0,c=I), m=I
  float alphi = rdlane(Ai2[IH][ILo], I);
  float SI = rdlane(S, I);                // col-I norm^2 over rows >= I
  float xnorm2 = fmaxf(SI - fmaf(alphr, alphr, alphi * alphi), 0.f);
  risky = risky || (fabsf(alphr) < 2e-4f);

  // ---- clarfg scalars (uniform). u unnormalized: u_I = alpha-beta,
  //      tau' = tau/|alpha-beta|^2; apply H^H: a -= conj(tau')(u^H a)u ----
  float ctr, cti, dr, di, beta_s;
  if (xnorm2 == 0.f && alphi == 0.f) {
    ctr = 0.f; cti = 0.f; dr = 0.f; di = 0.f;
    beta_s = alphr;                       // H = I; diagonal stays alpha (real)
  } else {
    float nrm = __builtin_amdgcn_sqrtf(
        fmaf(alphr, alphr, fmaf(alphi, alphi, xnorm2)));
    float beta = (alphr >= 0.f) ? -nrm : nrm;   // -SIGN(nrm, alphr)
    float rbeta = __builtin_amdgcn_rcpf(beta);
    float tr = (beta - alphr) * rbeta;
    float ti = -alphi * rbeta;
    dr = alphr - beta;  di = alphi;
    float inv = __builtin_amdgcn_rcpf(fmaf(dr, dr, di * di));
    ctr = tr * inv;
    cti = -(ti * inv);                    // conj(tau')
    beta_s = beta;
  }
  float rbq = __builtin_amdgcn_rcpf(beta_s);  // 1/R[I,I] for the solve

  // ---- broadcast u: lane (g,c) <- lane (g,I); fixup; accumulate dot ----
  v2f ur2[8], ui2[8];
  v2f prv = z2, piv = z2;
#pragma unroll
  for (int h = 0; h < 8; ++h) {
    v2f t, s;
    t[0] = dswz<SWZ>(Ar2[h][0]);
    t[1] = dswz<SWZ>(Ar2[h][1]);
    s[0] = dswz<SWZ>(Ai2[h][0]);
    s[1] = dswz<SWZ>(Ai2[h][1]);
    // fixups (g==0 receivers only): rows < I -> 0, row I -> (dr,di)
    if constexpr (I > 0) {
      if (h < IH) {
        t = g0 ? z2 : t;
        s = g0 ? z2 : s;
      }
    }
    if (h == IH) {
      if constexpr (ILo == 1) {           // pair IH = (I-1, I)
        t[0] = g0 ? 0.f : t[0];
        s[0] = g0 ? 0.f : s[0];
        t[1] = g0 ? dr : t[1];
        s[1] = g0 ? di : s[1];
      } else {                            // pair IH = (I, I+1)
        t[0] = g0 ? dr : t[0];
        s[0] = g0 ? di : s[0];
      }
    }
    ur2[h] = t;  ui2[h] = s;
    // p = u^H a_c (packed)
    prv = pkfma(t, Ar2[h], pkfma(s, Ai2[h], prv));
    piv = pkfma(t, Ai2[h], pkfma(-s, Ar2[h], piv));
  }
  float pr = prv[0] + prv[1];
  float pi = piv[0] + piv[1];
  pr = plswap16_addf(pr);  pr = plswap32_addf(pr);
  pi = plswap16_addf(pi);  pi = plswap32_addf(pi);
  const bool cle = (c <= I);
  pr = cle ? 0.f : pr;
  pi = cle ? 0.f : pi;

  // ---- w = conj(tau')*p (per-lane); update A (packed) ----
  float wr = fmaf(ctr, pr, -(cti * pi));
  float wi = fmaf(ctr, pi, cti * pr);
  const v2f wrv = splat2(wr), wiv = splat2(wi);
#pragma unroll
  for (int h = 0; h < 8; ++h) {
    Ar2[h] = pkfma(-wrv, ur2[h], pkfma(wiv, ui2[h], Ar2[h]));
    Ai2[h] = pkfma(-wrv, ui2[h], pkfma(-wiv, ur2[h], Ai2[h]));
  }

  // ---- solve push: q_I = P(c==I)/beta; P_c -= q_I * R[I,c] ----
  // R[I,c] at lane (0,c), reg (IH,ILo) post-update -> bpermute(src=c).
  float rr = __int_as_float(
      __builtin_amdgcn_ds_bpermute(bpaR, __float_as_int(Ar2[IH][ILo])));
  float ri = __int_as_float(
      __builtin_amdgcn_ds_bpermute(bpaR, __float_as_int(Ai2[IH][ILo])));
  const bool ceq = (c == I);
  const bool clt = (c < I);
  rr = ceq ? (beta_s - 1.f) : rr;  // P - P*rbq*(beta-1) = P/beta = q
  rr = clt ? 0.f : rr;             // finished Q columns: no-op
  ri = cle ? 0.f : ri;             // c==I wants ri=0 too

  // norm downdate for next step: S(rows>=I+1) = S(rows>=I) - |R[I,c]|^2.
  // (c<=I entries become garbage; never read again — future steps read c>I.)
  S = S - fmaf(rr, rr, ri * ri);

  // fold uniform 1/beta into the broadcast R value (replaces 32 muls)
  const v2f rrv = splat2(rr * rbq), riv = splat2(ri * rbq);

  // P-update with the column-I broadcast fused in (no br2/bi2 arrays)
#pragma unroll
  for (int h = 0; h < 8; ++h) {
    v2f br, bi;
    br[0] = dswz<SWZ>(Pr2[h][0]);
    br[1] = dswz<SWZ>(Pr2[h][1]);
    bi[0] = dswz<SWZ>(Pi2[h][0]);
    bi[1] = dswz<SWZ>(Pi2[h][1]);
    Pr2[h] = pkfma(-br, rrv, pkfma(bi, riv, Pr2[h]));
    Pi2[h] = pkfma(-br, riv, pkfma(-bi, rrv, Pi2[h]));
  }
}

// =====================================================================
// Fused single-dispatch kernel, (g,c) layout, packed row-pairs.
// =====================================================================
__global__ __launch_bounds__(256)
__attribute__((amdgpu_waves_per_eu(4)))
void qr_fused(const float* __restrict__ x, float* __restrict__ out, int B) {
  const int lane = threadIdx.x & 63;
  const int wave = threadIdx.x >> 6;
  const int b = blockIdx.x * 4 + wave;
  if (b >= B) return;
  const int c = lane & 15;
  const int gbase = lane & 48;     // 16*g
  const int bpaR = c << 2;         // bpermute addr: src lane = c (g=0)

  // load: lane (g,c) <- rows [gbase, gbase+16) of column c (row-pair packed)
  const float2* xp = reinterpret_cast<const float2*>(x) +
                     (size_t)b * (Mrows * Rcols) + (size_t)gbase * Rcols + c;
  v2f Ar2[8], Ai2[8], Pr2[8], Pi2[8];
#pragma unroll
  for (int h = 0; h < 8; ++h) {
    float2 t0 = xp[(2 * h) * Rcols];
    float2 t1 = xp[(2 * h + 1) * Rcols];
    v2f r, s;
    r[0] = t0.x;  r[1] = t1.x;
    s[0] = t0.y;  s[1] = t1.y;
    Ar2[h] = r;  Ai2[h] = s;
    Pr2[h] = r;  Pi2[h] = s;
  }

  // initial per-column norm^2 (rows >= 0), folded within the column
  v2f s2 = splat2(0.f);
#pragma unroll
  for (int h = 0; h < 8; ++h) {
    s2 = pkfma(Ar2[h], Ar2[h], pkfma(Ai2[h], Ai2[h], s2));
  }
  float S = s2[0] + s2[1];
  S = plswap16_addf(S);
  S = plswap32_addf(S);

  bool risky = false;
  qr_step<0>(lane, Ar2, Ai2, Pr2, Pi2, S, bpaR, risky);
  qr_step<1>(lane, Ar2, Ai2, Pr2, Pi2, S, bpaR, risky);
  qr_step<2>(lane, Ar2, Ai2, Pr2, Pi2, S, bpaR, risky);
  qr_step<3>(lane, Ar2, Ai2, Pr2, Pi2, S, bpaR, risky);
  qr_step<4>(lane, Ar2, Ai2, Pr2, Pi2, S, bpaR, risky);
  qr_step<5>(lane, Ar2, Ai2, Pr2, Pi2, S, bpaR, risky);
  qr_step<6>(lane, Ar2, Ai2, Pr2, Pi2, S, bpaR, risky);
  qr_step<7>(lane, Ar2, Ai2, Pr2, Pi2, S, bpaR, risky);
  qr_step<8>(lane, Ar2, Ai2, Pr2, Pi2, S, bpaR, risky);
  qr_step<9>(lane, Ar2, Ai2, Pr2, Pi2, S, bpaR, risky);
  qr_step<10>(lane, Ar2, Ai2, Pr2, Pi2, S, bpaR, risky);
  qr_step<11>(lane, Ar2, Ai2, Pr2, Pi2, S, bpaR, risky);
  qr_step<12>(lane, Ar2, Ai2, Pr2, Pi2, S, bpaR, risky);
  qr_step<13>(lane, Ar2, Ai2, Pr2, Pi2, S, bpaR, risky);
  qr_step<14>(lane, Ar2, Ai2, Pr2, Pi2, S, bpaR, risky);
  qr_step<15>(lane, Ar2, Ai2, Pr2, Pi2, S, bpaR, risky);

  if (risky) {  // wave-uniform (~0.26% of waves): exact fp64 redo
    qr_f64_fused(x, out, b, lane);
    return;
  }

  // store: P now holds Q
  float2* op = reinterpret_cast<float2*>(out) +
               (size_t)b * (Mrows * Rcols) + (size_t)gbase * Rcols + c;
#pragma unroll
  for (int h = 0; h < 8; ++h) {
    op[(2 * h) * Rcols] = make_float2(Pr2[h][0], Pi2[h][0]);
    op[(2 * h + 1) * Rcols] = make_float2(Pr2[h][1], Pi2[h][1]);
  }
}

extern "C" void kernel_launch(void* const* d_in, const int* in_sizes, int n_in,
                              void* d_out, int out_size, void* d_ws,
                              size_t ws_size, hipStream_t stream) {
  const float* x = (const float*)d_in[0];
  float* out = (float*)d_out;
  const int B = in_sizes[0] / (Mrows * Rcols * 2);
  dim3 block(256);  // 4 waves -> 4 batch elements per block
  dim3 grid((B + 3) / 4);
  qr_fused<<<grid, block, 0, stream>>>(x, out, B);
}

// Round 14
// 590.897 us; speedup vs baseline: 2.1095x; 2.1095x over previous
//
#include <hip/hip_runtime.h>

// Batched complex QR (Householder, LAPACK clarfg/cgeqr2 convention).
// v14: REVERT to v12 exactly (the proven best: 546.6us total, 277us dispatch).
// Round-13 post-mortem: waves_per_eu(4) forced VGPR to 64 -> the ~120-value
// live set spilled to scratch: 4.3 GB HBM round-trip/launch (53% of peak BW),
// VALUBusy 16%, dur 1020us. Knob landscape now fully mapped:
//   (2,2) = 326us (occupancy-capped, latency-exposed)
//   (3)   = 277us (spill-free, 26.5% occ, 62% busy)  <- optimum
//   (4)   = 1020us (spill catastrophe)
// (3) sits exactly at the occupancy-vs-register frontier for this live set.
//
// Layout recap: lane = g*16 + c; lane holds rows [16g,16g+16) of column c
// as 8 float2 row-pairs; v_pk_fma_f32 throughout; incremental norm downdate;
// unnormalized u + ds_swizzle (I<<5)|0x10 broadcasts; solve-push with
// Rbc=beta-1 trick; fp64 inline redo for |Re(alpha_i)| < 2e-4 (~0.26%).

constexpr int Mrows = 64;
constexpr int Rcols = 16;

typedef int v2i __attribute__((ext_vector_type(2)));
typedef float v2f __attribute__((ext_vector_type(2)));

#if defined(__has_builtin)
#if __has_builtin(__builtin_amdgcn_permlane16_swap)
#define USE_PL16 1
#else
#define USE_PL16 0
#endif
#if __has_builtin(__builtin_amdgcn_permlane32_swap)
#define USE_PL32 1
#else
#define USE_PL32 0
#endif
#else
#define USE_PL16 0
#define USE_PL32 0
#endif

__device__ __forceinline__ float rdlane(float v, int srclane) {
  return __int_as_float(__builtin_amdgcn_readlane(__float_as_int(v), srclane));
}

// v[l] + v[l^16]  (column-preserving: (g,c) <-> (g^1,c))
__device__ __forceinline__ float plswap16_addf(float v) {
#if USE_PL16
  v2i r = __builtin_amdgcn_permlane16_swap(__float_as_int(v), __float_as_int(v),
                                           false, false);
  return __int_as_float(r[0]) + __int_as_float(r[1]);
#else
  return v + __shfl_xor(v, 16, 64);
#endif
}

// v[l] + v[l^32]  ((g,c) <-> (g^2,c))
__device__ __forceinline__ float plswap32_addf(float v) {
#if USE_PL32
  v2i r = __builtin_amdgcn_permlane32_swap(__float_as_int(v), __float_as_int(v),
                                           false, false);
  return __int_as_float(r[0]) + __int_as_float(r[1]);
#else
  return v + __shfl_xor(v, 32, 64);
#endif
}

// Packed fp32 fma: one v_pk_fma_f32 per call.
__device__ __forceinline__ v2f pkfma(v2f a, v2f b, v2f c) {
#if defined(__has_builtin) && __has_builtin(__builtin_elementwise_fma)
  return __builtin_elementwise_fma(a, b, c);
#else
  v2f r;
  r[0] = fmaf(a[0], b[0], c[0]);
  r[1] = fmaf(a[1], b[1], c[1]);
  return r;
#endif
}

__device__ __forceinline__ v2f splat2(float s) { v2f r; r[0] = s; r[1] = s; return r; }

// ds_swizzle with compile-time immediate (builtin requires a literal const).
template <int IMM>
__device__ __forceinline__ float dswz(float v) {
  return __int_as_float(__builtin_amdgcn_ds_swizzle(__float_as_int(v), IMM));
}

// ---------------- fp64 helpers (proven v8/v9 path, unchanged) ----------------
template <int CTRL, int RM>
__device__ __forceinline__ double dpp_dadd(double v) {
  union { double d; int i[2]; } u, s;
  u.d = v;
  s.i[0] = __builtin_amdgcn_update_dpp(0, u.i[0], CTRL, RM, 0xF, true);
  s.i[1] = __builtin_amdgcn_update_dpp(0, u.i[1], CTRL, RM, 0xF, true);
  return v + s.d;
}

__device__ __forceinline__ double rdlaned(double v, int srclane) {
  union { double d; int i[2]; } u, r;
  u.d = v;
  r.i[0] = __builtin_amdgcn_readlane(u.i[0], srclane);
  r.i[1] = __builtin_amdgcn_readlane(u.i[1], srclane);
  return r.d;
}

__device__ __forceinline__ double wsum64d_fast(double v) {
  v = dpp_dadd<0xB1, 0xF>(v);
  v = dpp_dadd<0x4E, 0xF>(v);
  v = dpp_dadd<0x141, 0xF>(v);
  v = dpp_dadd<0x140, 0xF>(v);
  v = dpp_dadd<0x142, 0xA>(v);
  v = dpp_dadd<0x143, 0xC>(v);
  return rdlaned(v, 63);
}

// =====================================================================
// FP64 redo (rare, ~0.26% of waves): old row-per-lane layout, proven.
// =====================================================================
__device__ void qr_f64_fused(const float* __restrict__ x,
                             float* __restrict__ out, int b, int lane) {
  const float4* xp = reinterpret_cast<const float4*>(
      x + (size_t)b * (Mrows * Rcols * 2) + (size_t)lane * (Rcols * 2));
  double xr[Rcols], xi[Rcols], ar[Rcols], ai[Rcols];
#pragma unroll
  for (int k = 0; k < Rcols / 2; ++k) {
    float4 t = xp[k];
    xr[2 * k] = (double)t.x;      xi[2 * k] = (double)t.y;
    xr[2 * k + 1] = (double)t.z;  xi[2 * k + 1] = (double)t.w;
  }
#pragma unroll
  for (int j = 0; j < Rcols; ++j) { ar[j] = xr[j]; ai[j] = xi[j]; }

#pragma unroll
  for (int i = 0; i < Rcols; ++i) {
    double cr = ar[i], ci = ai[i];
    double sq = (lane > i) ? (cr * cr + ci * ci) : 0.0;
    double xnorm2 = wsum64d_fast(sq);
    double alphr = rdlaned(cr, i);
    double alphi = rdlaned(ci, i);

    double tr, ti;
    if (xnorm2 == 0.0 && alphi == 0.0) {
      tr = 0.0;  ti = 0.0;
    } else {
      double nrm = sqrt(alphr * alphr + alphi * alphi + xnorm2);
      double beta = (alphr >= 0.0) ? -nrm : nrm;
      double rb = 1.0 / beta;
      tr = (beta - alphr) * rb;
      ti = -alphi * rb;
      double dr = alphr - beta, di = alphi;
      double inv = 1.0 / (dr * dr + di * di);
      double sr = dr * inv, si = -di * inv;
      if (lane > i) {
        double nr = cr * sr - ci * si;
        double ni = cr * si + ci * sr;
        ar[i] = nr;
        ai[i] = ni;
      }
      if (lane == i) { ar[i] = beta; ai[i] = 0.0; }
    }

    double vr = (lane == i) ? 1.0 : ((lane > i) ? ar[i] : 0.0);
    double vi = (lane == i) ? 0.0 : ((lane > i) ? ai[i] : 0.0);
    const double ctr = tr, cti = -ti;
#pragma unroll
    for (int j = i + 1; j < Rcols; ++j) {
      double pr = fma(vr, ar[j], vi * ai[j]);
      double pi = fma(vr, ai[j], -(vi * ar[j]));
      pr = wsum64d_fast(pr);
      pi = wsum64d_fast(pi);
      double wr = fma(ctr, pr, -(cti * pi));
      double wi = fma(ctr, pi, cti * pr);
      ar[j] = fma(-wr, vr, fma(wi, vi, ar[j]));
      ai[j] = fma(-wr, vi, fma(-wi, vr, ai[j]));
    }

    double swr = xr[i], swi = xi[i];
#pragma unroll
    for (int k = 0; k < Rcols; ++k) {
      if (k >= i) break;
      double rr = rdlaned(ar[i], k);
      double ri = rdlaned(ai[i], k);
      swr = fma(-xr[k], rr, fma(xi[k], ri, swr));
      swi = fma(-xr[k], ri, fma(-xi[k], rr, swi));
    }
    double rbd = 1.0 / rdlaned(ar[i], i);
    xr[i] = swr * rbd;
    xi[i] = swi * rbd;
  }

  float4* op = reinterpret_cast<float4*>(
      out + (size_t)b * (Mrows * Rcols * 2) + (size_t)lane * (Rcols * 2));
#pragma unroll
  for (int k = 0; k < Rcols / 2; ++k) {
    op[k] = make_float4((float)xr[2 * k], (float)xi[2 * k],
                        (float)xr[2 * k + 1], (float)xi[2 * k + 1]);
  }
}

// =====================================================================
// One Householder step, (g,c) layout, row-pair packed. I compile-time.
// S = per-lane running norm^2 of own column over rows >= I (downdated).
// =====================================================================
template <int I>
__device__ __forceinline__ void qr_step(int lane,
                                        v2f (&Ar2)[8], v2f (&Ai2)[8],
                                        v2f (&Pr2)[8], v2f (&Pi2)[8],
                                        float& S, int bpaR, bool& risky) {
  const int c = lane & 15;
  const bool g0 = (lane < 16);
  constexpr int IH = I / 2;
  constexpr int ILo = I % 2;
  constexpr int SWZ = (I << 5) | 0x10;  // src = (l & 0x10) | I, g-preserving
  const v2f z2 = splat2(0.f);

  // ---- alpha and trailing norm (from downdated S) ----
  float alphr = rdlane(Ar2[IH][ILo], I);  // A[I][I]: lane I=(g0,c=I), m=I
  float alphi = rdlane(Ai2[IH][ILo], I);
  float SI = rdlane(S, I);                // col-I norm^2 over rows >= I
  float xnorm2 = fmaxf(SI - fmaf(alphr, alphr, alphi * alphi), 0.f);
  risky = risky || (fabsf(alphr) < 2e-4f);

  // ---- clarfg scalars (uniform). u unnormalized: u_I = alpha-beta,
  //      tau' = tau/|alpha-beta|^2; apply H^H: a -= conj(tau')(u^H a)u ----
  float ctr, cti, dr, di, beta_s;
  if (xnorm2 == 0.f && alphi == 0.f) {
    ctr = 0.f; cti = 0.f; dr = 0.f; di = 0.f;
    beta_s = alphr;                       // H = I; diagonal stays alpha (real)
  } else {
    float nrm = __builtin_amdgcn_sqrtf(
        fmaf(alphr, alphr, fmaf(alphi, alphi, xnorm2)));
    float beta = (alphr >= 0.f) ? -nrm : nrm;   // -SIGN(nrm, alphr)
    float rbeta = __builtin_amdgcn_rcpf(beta);
    float tr = (beta - alphr) * rbeta;
    float ti = -alphi * rbeta;
    dr = alphr - beta;  di = alphi;
    float inv = __builtin_amdgcn_rcpf(fmaf(dr, dr, di * di));
    ctr = tr * inv;
    cti = -(ti * inv);                    // conj(tau')
    beta_s = beta;
  }
  float rbq = __builtin_amdgcn_rcpf(beta_s);  // 1/R[I,I] for the solve

  // ---- broadcast u: lane (g,c) <- lane (g,I); fixup; accumulate dot ----
  v2f ur2[8], ui2[8];
  v2f prv = z2, piv = z2;
#pragma unroll
  for (int h = 0; h < 8; ++h) {
    v2f t, s;
    t[0] = dswz<SWZ>(Ar2[h][0]);
    t[1] = dswz<SWZ>(Ar2[h][1]);
    s[0] = dswz<SWZ>(Ai2[h][0]);
    s[1] = dswz<SWZ>(Ai2[h][1]);
    // fixups (g==0 receivers only): rows < I -> 0, row I -> (dr,di)
    if constexpr (I > 0) {
      if (h < IH) {
        t = g0 ? z2 : t;
        s = g0 ? z2 : s;
      }
    }
    if (h == IH) {
      if constexpr (ILo == 1) {           // pair IH = (I-1, I)
        t[0] = g0 ? 0.f : t[0];
        s[0] = g0 ? 0.f : s[0];
        t[1] = g0 ? dr : t[1];
        s[1] = g0 ? di : s[1];
      } else {                            // pair IH = (I, I+1)
        t[0] = g0 ? dr : t[0];
        s[0] = g0 ? di : s[0];
      }
    }
    ur2[h] = t;  ui2[h] = s;
    // p = u^H a_c (packed)
    prv = pkfma(t, Ar2[h], pkfma(s, Ai2[h], prv));
    piv = pkfma(t, Ai2[h], pkfma(-s, Ar2[h], piv));
  }
  float pr = prv[0] + prv[1];
  float pi = piv[0] + piv[1];
  pr = plswap16_addf(pr);  pr = plswap32_addf(pr);
  pi = plswap16_addf(pi);  pi = plswap32_addf(pi);
  const bool cle = (c <= I);
  pr = cle ? 0.f : pr;
  pi = cle ? 0.f : pi;

  // ---- w = conj(tau')*p (per-lane); update A (packed) ----
  float wr = fmaf(ctr, pr, -(cti * pi));
  float wi = fmaf(ctr, pi, cti * pr);
  const v2f wrv = splat2(wr), wiv = splat2(wi);
#pragma unroll
  for (int h = 0; h < 8; ++h) {
    Ar2[h] = pkfma(-wrv, ur2[h], pkfma(wiv, ui2[h], Ar2[h]));
    Ai2[h] = pkfma(-wrv, ui2[h], pkfma(-wiv, ur2[h], Ai2[h]));
  }

  // ---- solve push: q_I = P(c==I)/beta; P_c -= q_I * R[I,c] ----
  // R[I,c] at lane (0,c), reg (IH,ILo) post-update -> bpermute(src=c).
  float rr = __int_as_float(
      __builtin_amdgcn_ds_bpermute(bpaR, __float_as_int(Ar2[IH][ILo])));
  float ri = __int_as_float(
      __builtin_amdgcn_ds_bpermute(bpaR, __float_as_int(Ai2[IH][ILo])));
  const bool ceq = (c == I);
  const bool clt = (c < I);
  rr = ceq ? (beta_s - 1.f) : rr;  // P - P*rbq*(beta-1) = P/beta = q
  rr = clt ? 0.f : rr;             // finished Q columns: no-op
  ri = cle ? 0.f : ri;             // c==I wants ri=0 too

  // norm downdate for next step: S(rows>=I+1) = S(rows>=I) - |R[I,c]|^2.
  // (c<=I entries become garbage; never read again — future steps read c>I.)
  S = S - fmaf(rr, rr, ri * ri);

  // fold uniform 1/beta into the broadcast R value (replaces 32 muls)
  const v2f rrv = splat2(rr * rbq), riv = splat2(ri * rbq);

  // P-update with the column-I broadcast fused in (no br2/bi2 arrays)
#pragma unroll
  for (int h = 0; h < 8; ++h) {
    v2f br, bi;
    br[0] = dswz<SWZ>(Pr2[h][0]);
    br[1] = dswz<SWZ>(Pr2[h][1]);
    bi[0] = dswz<SWZ>(Pi2[h][0]);
    bi[1] = dswz<SWZ>(Pi2[h][1]);
    Pr2[h] = pkfma(-br, rrv, pkfma(bi, riv, Pr2[h]));
    Pi2[h] = pkfma(-br, riv, pkfma(-bi, rrv, Pi2[h]));
  }
}

// =====================================================================
// Fused single-dispatch kernel, (g,c) layout, packed row-pairs.
// =====================================================================
__global__ __launch_bounds__(256)
__attribute__((amdgpu_waves_per_eu(3)))
void qr_fused(const float* __restrict__ x, float* __restrict__ out, int B) {
  const int lane = threadIdx.x & 63;
  const int wave = threadIdx.x >> 6;
  const int b = blockIdx.x * 4 + wave;
  if (b >= B) return;
  const int c = lane & 15;
  const int gbase = lane & 48;     // 16*g
  const int bpaR = c << 2;         // bpermute addr: src lane = c (g=0)

  // load: lane (g,c) <- rows [gbase, gbase+16) of column c (row-pair packed)
  const float2* xp = reinterpret_cast<const float2*>(x) +
                     (size_t)b * (Mrows * Rcols) + (size_t)gbase * Rcols + c;
  v2f Ar2[8], Ai2[8], Pr2[8], Pi2[8];
#pragma unroll
  for (int h = 0; h < 8; ++h) {
    float2 t0 = xp[(2 * h) * Rcols];
    float2 t1 = xp[(2 * h + 1) * Rcols];
    v2f r, s;
    r[0] = t0.x;  r[1] = t1.x;
    s[0] = t0.y;  s[1] = t1.y;
    Ar2[h] = r;  Ai2[h] = s;
    Pr2[h] = r;  Pi2[h] = s;
  }

  // initial per-column norm^2 (rows >= 0), folded within the column
  v2f s2 = splat2(0.f);
#pragma unroll
  for (int h = 0; h < 8; ++h) {
    s2 = pkfma(Ar2[h], Ar2[h], pkfma(Ai2[h], Ai2[h], s2));
  }
  float S = s2[0] + s2[1];
  S = plswap16_addf(S);
  S = plswap32_addf(S);

  bool risky = false;
  qr_step<0>(lane, Ar2, Ai2, Pr2, Pi2, S, bpaR, risky);
  qr_step<1>(lane, Ar2, Ai2, Pr2, Pi2, S, bpaR, risky);
  qr_step<2>(lane, Ar2, Ai2, Pr2, Pi2, S, bpaR, risky);
  qr_step<3>(lane, Ar2, Ai2, Pr2, Pi2, S, bpaR, risky);
  qr_step<4>(lane, Ar2, Ai2, Pr2, Pi2, S, bpaR, risky);
  qr_step<5>(lane, Ar2, Ai2, Pr2, Pi2, S, bpaR, risky);
  qr_step<6>(lane, Ar2, Ai2, Pr2, Pi2, S, bpaR, risky);
  qr_step<7>(lane, Ar2, Ai2, Pr2, Pi2, S, bpaR, risky);
  qr_step<8>(lane, Ar2, Ai2, Pr2, Pi2, S, bpaR, risky);
  qr_step<9>(lane, Ar2, Ai2, Pr2, Pi2, S, bpaR, risky);
  qr_step<10>(lane, Ar2, Ai2, Pr2, Pi2, S, bpaR, risky);
  qr_step<11>(lane, Ar2, Ai2, Pr2, Pi2, S, bpaR, risky);
  qr_step<12>(lane, Ar2, Ai2, Pr2, Pi2, S, bpaR, risky);
  qr_step<13>(lane, Ar2, Ai2, Pr2, Pi2, S, bpaR, risky);
  qr_step<14>(lane, Ar2, Ai2, Pr2, Pi2, S, bpaR, risky);
  qr_step<15>(lane, Ar2, Ai2, Pr2, Pi2, S, bpaR, risky);

  if (risky) {  // wave-uniform (~0.26% of waves): exact fp64 redo
    qr_f64_fused(x, out, b, lane);
    return;
  }

  // store: P now holds Q
  float2* op = reinterpret_cast<float2*>(out) +
               (size_t)b * (Mrows * Rcols) + (size_t)gbase * Rcols + c;
#pragma unroll
  for (int h = 0; h < 8; ++h) {
    op[(2 * h) * Rcols] = make_float2(Pr2[h][0], Pi2[h][0]);
    op[(2 * h + 1) * Rcols] = make_float2(Pr2[h][1], Pi2[h][1]);
  }
}

extern "C" void kernel_launch(void* const* d_in, const int* in_sizes, int n_in,
                              void* d_out, int out_size, void* d_ws,
                              size_t ws_size, hipStream_t stream) {
  const float* x = (const float*)d_in[0];
  float* out = (float*)d_out;
  const int B = in_sizes[0] / (Mrows * Rcols * 2);
  dim3 block(256);  // 4 waves -> 4 batch elements per block
  dim3 grid((B + 3) / 4);
  qr_fused<<<grid, block, 0, stream>>>(x, out, B);
}

// Round 15
// 537.700 us; speedup vs baseline: 2.3182x; 1.0989x over previous
//
#include <hip/hip_runtime.h>

// Batched complex QR (Householder, LAPACK clarfg/cgeqr2 convention).
// v15: v14/v12 minus the ur2/ui2 temp arrays (-32 live registers).
// Round-14 post-mortem: v14 ≡ v12 binary measured 365us vs 277us dispatch —
// run-to-run noise is ~30%; only >=15% modeled changes are worth a round.
// Remaining modeled overhead: live set ~120 > 84 arch VGPRs -> overflow in
// unified-file AGPRs, paying v_accvgpr_read/write on access (~1.5-2k
// instrs/wave; WRITE=262MB exactly proves no scratch). Fix: recompute the
// u-broadcast swizzles in the A-update loop instead of caching them.
// Valid because w==0 for c<=I: the swizzle source lanes (g,I) are invariant
// under the A-update, so a re-swizzle reads identical values. +32 DS/step
// (DS pipe has headroom: ~6k cyc vs VALU ~13k), -32 live regs.
//
// Layout recap: lane = g*16 + c; lane holds rows [16g,16g+16) of column c
// as 8 float2 row-pairs; v_pk_fma_f32 throughout; incremental norm downdate;
// unnormalized u + ds_swizzle (I<<5)|0x10 broadcasts; solve-push with
// Rbc=beta-1 trick; fp64 inline redo for |Re(alpha_i)| < 2e-4 (~0.26%).
// waves_per_eu knob mapped: (2,2)=326us, (3)=277us best, (4)=spill 1020us.

constexpr int Mrows = 64;
constexpr int Rcols = 16;

typedef int v2i __attribute__((ext_vector_type(2)));
typedef float v2f __attribute__((ext_vector_type(2)));

#if defined(__has_builtin)
#if __has_builtin(__builtin_amdgcn_permlane16_swap)
#define USE_PL16 1
#else
#define USE_PL16 0
#endif
#if __has_builtin(__builtin_amdgcn_permlane32_swap)
#define USE_PL32 1
#else
#define USE_PL32 0
#endif
#else
#define USE_PL16 0
#define USE_PL32 0
#endif

__device__ __forceinline__ float rdlane(float v, int srclane) {
  return __int_as_float(__builtin_amdgcn_readlane(__float_as_int(v), srclane));
}

// v[l] + v[l^16]  (column-preserving: (g,c) <-> (g^1,c))
__device__ __forceinline__ float plswap16_addf(float v) {
#if USE_PL16
  v2i r = __builtin_amdgcn_permlane16_swap(__float_as_int(v), __float_as_int(v),
                                           false, false);
  return __int_as_float(r[0]) + __int_as_float(r[1]);
#else
  return v + __shfl_xor(v, 16, 64);
#endif
}

// v[l] + v[l^32]  ((g,c) <-> (g^2,c))
__device__ __forceinline__ float plswap32_addf(float v) {
#if USE_PL32
  v2i r = __builtin_amdgcn_permlane32_swap(__float_as_int(v), __float_as_int(v),
                                           false, false);
  return __int_as_float(r[0]) + __int_as_float(r[1]);
#else
  return v + __shfl_xor(v, 32, 64);
#endif
}

// Packed fp32 fma: one v_pk_fma_f32 per call.
__device__ __forceinline__ v2f pkfma(v2f a, v2f b, v2f c) {
#if defined(__has_builtin) && __has_builtin(__builtin_elementwise_fma)
  return __builtin_elementwise_fma(a, b, c);
#else
  v2f r;
  r[0] = fmaf(a[0], b[0], c[0]);
  r[1] = fmaf(a[1], b[1], c[1]);
  return r;
#endif
}

__device__ __forceinline__ v2f splat2(float s) { v2f r; r[0] = s; r[1] = s; return r; }

// ds_swizzle with compile-time immediate (builtin requires a literal const).
template <int IMM>
__device__ __forceinline__ float dswz(float v) {
  return __int_as_float(__builtin_amdgcn_ds_swizzle(__float_as_int(v), IMM));
}

// Broadcast u chunk for row-pair h from lane (g,I), with clarfg fixups.
// Source lanes (c==I) are invariant under the A-update (w==0 for c<=I),
// so this can be called both before and after partial A-updates.
template <int I>
__device__ __forceinline__ void get_u(int h, bool g0, float dr, float di,
                                      const v2f (&Ar2)[8], const v2f (&Ai2)[8],
                                      v2f& t, v2f& s) {
  constexpr int IH = I / 2;
  constexpr int ILo = I % 2;
  constexpr int SWZ = (I << 5) | 0x10;  // src = (l & 0x10) | I, g-preserving
  t[0] = dswz<SWZ>(Ar2[h][0]);
  t[1] = dswz<SWZ>(Ar2[h][1]);
  s[0] = dswz<SWZ>(Ai2[h][0]);
  s[1] = dswz<SWZ>(Ai2[h][1]);
  const v2f z2 = splat2(0.f);
  // fixups (g==0 receivers only): rows < I -> 0, row I -> (dr,di)
  if (I > 0 && h < IH) {
    t = g0 ? z2 : t;
    s = g0 ? z2 : s;
  }
  if (h == IH) {
    if (ILo == 1) {                     // pair IH = (I-1, I)
      t[0] = g0 ? 0.f : t[0];
      s[0] = g0 ? 0.f : s[0];
      t[1] = g0 ? dr : t[1];
      s[1] = g0 ? di : s[1];
    } else {                            // pair IH = (I, I+1)
      t[0] = g0 ? dr : t[0];
      s[0] = g0 ? di : s[0];
    }
  }
}

// ---------------- fp64 helpers (proven v8/v9 path, unchanged) ----------------
template <int CTRL, int RM>
__device__ __forceinline__ double dpp_dadd(double v) {
  union { double d; int i[2]; } u, s;
  u.d = v;
  s.i[0] = __builtin_amdgcn_update_dpp(0, u.i[0], CTRL, RM, 0xF, true);
  s.i[1] = __builtin_amdgcn_update_dpp(0, u.i[1], CTRL, RM, 0xF, true);
  return v + s.d;
}

__device__ __forceinline__ double rdlaned(double v, int srclane) {
  union { double d; int i[2]; } u, r;
  u.d = v;
  r.i[0] = __builtin_amdgcn_readlane(u.i[0], srclane);
  r.i[1] = __builtin_amdgcn_readlane(u.i[1], srclane);
  return r.d;
}

__device__ __forceinline__ double wsum64d_fast(double v) {
  v = dpp_dadd<0xB1, 0xF>(v);
  v = dpp_dadd<0x4E, 0xF>(v);
  v = dpp_dadd<0x141, 0xF>(v);
  v = dpp_dadd<0x140, 0xF>(v);
  v = dpp_dadd<0x142, 0xA>(v);
  v = dpp_dadd<0x143, 0xC>(v);
  return rdlaned(v, 63);
}

// =====================================================================
// FP64 redo (rare, ~0.26% of waves): old row-per-lane layout, proven.
// =====================================================================
__device__ void qr_f64_fused(const float* __restrict__ x,
                             float* __restrict__ out, int b, int lane) {
  const float4* xp = reinterpret_cast<const float4*>(
      x + (size_t)b * (Mrows * Rcols * 2) + (size_t)lane * (Rcols * 2));
  double xr[Rcols], xi[Rcols], ar[Rcols], ai[Rcols];
#pragma unroll
  for (int k = 0; k < Rcols / 2; ++k) {
    float4 t = xp[k];
    xr[2 * k] = (double)t.x;      xi[2 * k] = (double)t.y;
    xr[2 * k + 1] = (double)t.z;  xi[2 * k + 1] = (double)t.w;
  }
#pragma unroll
  for (int j = 0; j < Rcols; ++j) { ar[j] = xr[j]; ai[j] = xi[j]; }

#pragma unroll
  for (int i = 0; i < Rcols; ++i) {
    double cr = ar[i], ci = ai[i];
    double sq = (lane > i) ? (cr * cr + ci * ci) : 0.0;
    double xnorm2 = wsum64d_fast(sq);
    double alphr = rdlaned(cr, i);
    double alphi = rdlaned(ci, i);

    double tr, ti;
    if (xnorm2 == 0.0 && alphi == 0.0) {
      tr = 0.0;  ti = 0.0;
    } else {
      double nrm = sqrt(alphr * alphr + alphi * alphi + xnorm2);
      double beta = (alphr >= 0.0) ? -nrm : nrm;
      double rb = 1.0 / beta;
      tr = (beta - alphr) * rb;
      ti = -alphi * rb;
      double dr = alphr - beta, di = alphi;
      double inv = 1.0 / (dr * dr + di * di);
      double sr = dr * inv, si = -di * inv;
      if (lane > i) {
        double nr = cr * sr - ci * si;
        double ni = cr * si + ci * sr;
        ar[i] = nr;
        ai[i] = ni;
      }
      if (lane == i) { ar[i] = beta; ai[i] = 0.0; }
    }

    double vr = (lane == i) ? 1.0 : ((lane > i) ? ar[i] : 0.0);
    double vi = (lane == i) ? 0.0 : ((lane > i) ? ai[i] : 0.0);
    const double ctr = tr, cti = -ti;
#pragma unroll
    for (int j = i + 1; j < Rcols; ++j) {
      double pr = fma(vr, ar[j], vi * ai[j]);
      double pi = fma(vr, ai[j], -(vi * ar[j]));
      pr = wsum64d_fast(pr);
      pi = wsum64d_fast(pi);
      double wr = fma(ctr, pr, -(cti * pi));
      double wi = fma(ctr, pi, cti * pr);
      ar[j] = fma(-wr, vr, fma(wi, vi, ar[j]));
      ai[j] = fma(-wr, vi, fma(-wi, vr, ai[j]));
    }

    double swr = xr[i], swi = xi[i];
#pragma unroll
    for (int k = 0; k < Rcols; ++k) {
      if (k >= i) break;
      double rr = rdlaned(ar[i], k);
      double ri = rdlaned(ai[i], k);
      swr = fma(-xr[k], rr, fma(xi[k], ri, swr));
      swi = fma(-xr[k], ri, fma(-xi[k], rr, swi));
    }
    double rbd = 1.0 / rdlaned(ar[i], i);
    xr[i] = swr * rbd;
    xi[i] = swi * rbd;
  }

  float4* op = reinterpret_cast<float4*>(
      out + (size_t)b * (Mrows * Rcols * 2) + (size_t)lane * (Rcols * 2));
#pragma unroll
  for (int k = 0; k < Rcols / 2; ++k) {
    op[k] = make_float4((float)xr[2 * k], (float)xi[2 * k],
                        (float)xr[2 * k + 1], (float)xi[2 * k + 1]);
  }
}

// =====================================================================
// One Householder step, (g,c) layout, row-pair packed. I compile-time.
// S = per-lane running norm^2 of own column over rows >= I (downdated).
// =====================================================================
template <int I>
__device__ __forceinline__ void qr_step(int lane,
                                        v2f (&Ar2)[8], v2f (&Ai2)[8],
                                        v2f (&Pr2)[8], v2f (&Pi2)[8],
                                        float& S, int bpaR, bool& risky) {
  const int c = lane & 15;
  const bool g0 = (lane < 16);
  constexpr int IH = I / 2;
  constexpr int ILo = I % 2;
  constexpr int SWZ = (I << 5) | 0x10;  // src = (l & 0x10) | I, g-preserving
  const v2f z2 = splat2(0.f);

  // ---- alpha and trailing norm (from downdated S) ----
  float alphr = rdlane(Ar2[IH][ILo], I);  // A[I][I]: lane I=(g0,c=I), m=I
  float alphi = rdlane(Ai2[IH][ILo], I);
  float SI = rdlane(S, I);                // col-I norm^2 over rows >= I
  float xnorm2 = fmaxf(SI - fmaf(alphr, alphr, alphi * alphi), 0.f);
  risky = risky || (fabsf(alphr) < 2e-4f);

  // ---- clarfg scalars (uniform). u unnormalized: u_I = alpha-beta,
  //      tau' = tau/|alpha-beta|^2; apply H^H: a -= conj(tau')(u^H a)u ----
  float ctr, cti, dr, di, beta_s;
  if (xnorm2 == 0.f && alphi == 0.f) {
    ctr = 0.f; cti = 0.f; dr = 0.f; di = 0.f;
    beta_s = alphr;                       // H = I; diagonal stays alpha (real)
  } else {
    float nrm = __builtin_amdgcn_sqrtf(
        fmaf(alphr, alphr, fmaf(alphi, alphi, xnorm2)));
    float beta = (alphr >= 0.f) ? -nrm : nrm;   // -SIGN(nrm, alphr)
    float rbeta = __builtin_amdgcn_rcpf(beta);
    float tr = (beta - alphr) * rbeta;
    float ti = -alphi * rbeta;
    dr = alphr - beta;  di = alphi;
    float inv = __builtin_amdgcn_rcpf(fmaf(dr, dr, di * di));
    ctr = tr * inv;
    cti = -(ti * inv);                    // conj(tau')
    beta_s = beta;
  }
  float rbq = __builtin_amdgcn_rcpf(beta_s);  // 1/R[I,I] for the solve

  // ---- p = u^H a_c: swizzle u on the fly (no cached u arrays) ----
  v2f prv = z2, piv = z2;
#pragma unroll
  for (int h = 0; h < 8; ++h) {
    v2f t, s;
    get_u<I>(h, g0, dr, di, Ar2, Ai2, t, s);
    prv = pkfma(t, Ar2[h], pkfma(s, Ai2[h], prv));
    piv = pkfma(t, Ai2[h], pkfma(-s, Ar2[h], piv));
  }
  float pr = prv[0] + prv[1];
  float pi = piv[0] + piv[1];
  pr = plswap16_addf(pr);  pr = plswap32_addf(pr);
  pi = plswap16_addf(pi);  pi = plswap32_addf(pi);
  const bool cle = (c <= I);
  pr = cle ? 0.f : pr;
  pi = cle ? 0.f : pi;

  // ---- w = conj(tau')*p (per-lane); update A, re-swizzling u ----
  // (valid: w==0 for c<=I, so source lanes (g,I) never change)
  float wr = fmaf(ctr, pr, -(cti * pi));
  float wi = fmaf(ctr, pi, cti * pr);
  const v2f wrv = splat2(wr), wiv = splat2(wi);
#pragma unroll
  for (int h = 0; h < 8; ++h) {
    v2f t, s;
    get_u<I>(h, g0, dr, di, Ar2, Ai2, t, s);
    Ar2[h] = pkfma(-wrv, t, pkfma(wiv, s, Ar2[h]));
    Ai2[h] = pkfma(-wrv, s, pkfma(-wiv, t, Ai2[h]));
  }

  // ---- solve push: q_I = P(c==I)/beta; P_c -= q_I * R[I,c] ----
  // R[I,c] at lane (0,c), reg (IH,ILo) post-update -> bpermute(src=c).
  float rr = __int_as_float(
      __builtin_amdgcn_ds_bpermute(bpaR, __float_as_int(Ar2[IH][ILo])));
  float ri = __int_as_float(
      __builtin_amdgcn_ds_bpermute(bpaR, __float_as_int(Ai2[IH][ILo])));
  const bool ceq = (c == I);
  const bool clt = (c < I);
  rr = ceq ? (beta_s - 1.f) : rr;  // P - P*rbq*(beta-1) = P/beta = q
  rr = clt ? 0.f : rr;             // finished Q columns: no-op
  ri = cle ? 0.f : ri;             // c==I wants ri=0 too

  // norm downdate for next step: S(rows>=I+1) = S(rows>=I) - |R[I,c]|^2.
  // (c<=I entries become garbage; never read again — future steps read c>I.)
  S = S - fmaf(rr, rr, ri * ri);

  // fold uniform 1/beta into the broadcast R value (replaces 32 muls)
  const v2f rrv = splat2(rr * rbq), riv = splat2(ri * rbq);

  // P-update with the column-I broadcast fused in (no temp arrays)
#pragma unroll
  for (int h = 0; h < 8; ++h) {
    v2f br, bi;
    br[0] = dswz<SWZ>(Pr2[h][0]);
    br[1] = dswz<SWZ>(Pr2[h][1]);
    bi[0] = dswz<SWZ>(Pi2[h][0]);
    bi[1] = dswz<SWZ>(Pi2[h][1]);
    Pr2[h] = pkfma(-br, rrv, pkfma(bi, riv, Pr2[h]));
    Pi2[h] = pkfma(-br, riv, pkfma(-bi, rrv, Pi2[h]));
  }
}

// =====================================================================
// Fused single-dispatch kernel, (g,c) layout, packed row-pairs.
// =====================================================================
__global__ __launch_bounds__(256)
__attribute__((amdgpu_waves_per_eu(3)))
void qr_fused(const float* __restrict__ x, float* __restrict__ out, int B) {
  const int lane = threadIdx.x & 63;
  const int wave = threadIdx.x >> 6;
  const int b = blockIdx.x * 4 + wave;
  if (b >= B) return;
  const int c = lane & 15;
  const int gbase = lane & 48;     // 16*g
  const int bpaR = c << 2;         // bpermute addr: src lane = c (g=0)

  // load: lane (g,c) <- rows [gbase, gbase+16) of column c (row-pair packed)
  const float2* xp = reinterpret_cast<const float2*>(x) +
                     (size_t)b * (Mrows * Rcols) + (size_t)gbase * Rcols + c;
  v2f Ar2[8], Ai2[8], Pr2[8], Pi2[8];
#pragma unroll
  for (int h = 0; h < 8; ++h) {
    float2 t0 = xp[(2 * h) * Rcols];
    float2 t1 = xp[(2 * h + 1) * Rcols];
    v2f r, s;
    r[0] = t0.x;  r[1] = t1.x;
    s[0] = t0.y;  s[1] = t1.y;
    Ar2[h] = r;  Ai2[h] = s;
    Pr2[h] = r;  Pi2[h] = s;
  }

  // initial per-column norm^2 (rows >= 0), folded within the column
  v2f s2 = splat2(0.f);
#pragma unroll
  for (int h = 0; h < 8; ++h) {
    s2 = pkfma(Ar2[h], Ar2[h], pkfma(Ai2[h], Ai2[h], s2));
  }
  float S = s2[0] + s2[1];
  S = plswap16_addf(S);
  S = plswap32_addf(S);

  bool risky = false;
  qr_step<0>(lane, Ar2, Ai2, Pr2, Pi2, S, bpaR, risky);
  qr_step<1>(lane, Ar2, Ai2, Pr2, Pi2, S, bpaR, risky);
  qr_step<2>(lane, Ar2, Ai2, Pr2, Pi2, S, bpaR, risky);
  qr_step<3>(lane, Ar2, Ai2, Pr2, Pi2, S, bpaR, risky);
  qr_step<4>(lane, Ar2, Ai2, Pr2, Pi2, S, bpaR, risky);
  qr_step<5>(lane, Ar2, Ai2, Pr2, Pi2, S, bpaR, risky);
  qr_step<6>(lane, Ar2, Ai2, Pr2, Pi2, S, bpaR, risky);
  qr_step<7>(lane, Ar2, Ai2, Pr2, Pi2, S, bpaR, risky);
  qr_step<8>(lane, Ar2, Ai2, Pr2, Pi2, S, bpaR, risky);
  qr_step<9>(lane, Ar2, Ai2, Pr2, Pi2, S, bpaR, risky);
  qr_step<10>(lane, Ar2, Ai2, Pr2, Pi2, S, bpaR, risky);
  qr_step<11>(lane, Ar2, Ai2, Pr2, Pi2, S, bpaR, risky);
  qr_step<12>(lane, Ar2, Ai2, Pr2, Pi2, S, bpaR, risky);
  qr_step<13>(lane, Ar2, Ai2, Pr2, Pi2, S, bpaR, risky);
  qr_step<14>(lane, Ar2, Ai2, Pr2, Pi2, S, bpaR, risky);
  qr_step<15>(lane, Ar2, Ai2, Pr2, Pi2, S, bpaR, risky);

  if (risky) {  // wave-uniform (~0.26% of waves): exact fp64 redo
    qr_f64_fused(x, out, b, lane);
    return;
  }

  // store: P now holds Q
  float2* op = reinterpret_cast<float2*>(out) +
               (size_t)b * (Mrows * Rcols) + (size_t)gbase * Rcols + c;
#pragma unroll
  for (int h = 0; h < 8; ++h) {
    op[(2 * h) * Rcols] = make_float2(Pr2[h][0], Pi2[h][0]);
    op[(2 * h + 1) * Rcols] = make_float2(Pr2[h][1], Pi2[h][1]);
  }
}

extern "C" void kernel_launch(void* const* d_in, const int* in_sizes, int n_in,
                              void* d_out, int out_size, void* d_ws,
                              size_t ws_size, hipStream_t stream) {
  const float* x = (const float*)d_in[0];
  float* out = (float*)d_out;
  const int B = in_sizes[0] / (Mrows * Rcols * 2);
  dim3 block(256);  // 4 waves -> 4 batch elements per block
  dim3 grid((B + 3) / 4);
  qr_fused<<<grid, block, 0, stream>>>(x, out, B);
}